// Round 8
// baseline (186.571 us; speedup 1.0000x reference)
//
#include <hip/hip_runtime.h>

constexpr int DIM  = 33;
constexpr int DIM2 = DIM * DIM;        // 1089
constexpr int DIM3 = DIM * DIM * DIM;  // 35937
constexpr int HW    = 1024 * 1024;
constexpr int BATCH = 8;
constexpr int GROUPS_PER_IMG = HW / 4;     // 262144 float4-groups per channel plane
constexpr unsigned LDS_BYTES = DIM3 * 4;   // 143748 B (fits 160 KiB/CU)

static_assert(256 * 1024 == GROUPS_PER_IMG, "grid must cover one image exactly");

// ---------------------------------------------------------------------------
// Tiny prep kernel: quantize+pack the LUT once into workspace.
// One dword per texel: ch0 bits[9:0], ch1 bits[19:10], ch2 bits[29:20].
// ---------------------------------------------------------------------------
__global__ __launch_bounds__(256) void lut_pack_kernel(
    const float* __restrict__ lut, unsigned int* __restrict__ packed)
{
    int i = blockIdx.x * blockDim.x + threadIdx.x;
    if (i < DIM3) {
        float v0 = lut[i];
        float v1 = lut[DIM3 + i];
        float v2 = lut[2 * DIM3 + i];
        unsigned q0 = (unsigned)(fminf(fmaxf(v0, 0.0f), 1.0f) * 1023.0f + 0.5f);
        unsigned q1 = (unsigned)(fminf(fmaxf(v1, 0.0f), 1.0f) * 1023.0f + 0.5f);
        unsigned q2 = (unsigned)(fminf(fmaxf(v2, 0.0f), 1.0f) * 1023.0f + 0.5f);
        packed[i] = q0 | (q1 << 10) | (q2 << 20);
    }
}

// ---------------------------------------------------------------------------
// Per-pixel trilinear interpolation against the packed LDS LUT.
// BYTE-IDENTICAL numerics to every verified 65us version.
// ---------------------------------------------------------------------------
__device__ __forceinline__ void lut_px(const unsigned int* sLut,
                                       float r, float g, float b,
                                       float& out0, float& out1, float& out2)
{
    const float invbin = 32.0f / 1.000001f;   // 1/binsize
    const float dq = 1.0f / 1023.0f;

    float tr = r * invbin;
    float tg = g * invbin;
    float tb = b * invbin;

    int ri = (int)tr;
    int gi = (int)tg;
    int bi = (int)tb;
    ri = ri < 0 ? 0 : (ri > DIM - 2 ? DIM - 2 : ri);
    gi = gi < 0 ? 0 : (gi > DIM - 2 ? DIM - 2 : gi);
    bi = bi < 0 ? 0 : (bi > DIM - 2 ? DIM - 2 : bi);

    float rd = tr - (float)ri;
    float gd = tg - (float)gi;
    float bd = tb - (float)bi;

    int base = bi * DIM2 + gi * DIM + ri;

    unsigned c000 = sLut[base];
    unsigned c001 = sLut[base + 1];
    unsigned c010 = sLut[base + DIM];
    unsigned c011 = sLut[base + DIM + 1];
    unsigned c100 = sLut[base + DIM2];
    unsigned c101 = sLut[base + DIM2 + 1];
    unsigned c110 = sLut[base + DIM2 + DIM];
    unsigned c111 = sLut[base + DIM2 + DIM + 1];

    float wr1 = rd, wr0 = 1.0f - rd;
    float wg1 = gd, wg0 = 1.0f - gd;
    float wb1 = bd, wb0 = 1.0f - bd;

    float w000 = wb0 * wg0 * wr0;
    float w001 = wb0 * wg0 * wr1;
    float w010 = wb0 * wg1 * wr0;
    float w011 = wb0 * wg1 * wr1;
    float w100 = wb1 * wg0 * wr0;
    float w101 = wb1 * wg0 * wr1;
    float w110 = wb1 * wg1 * wr0;
    float w111 = wb1 * wg1 * wr1;

    float a0 = w000 * (float)(c000 & 1023u) + w001 * (float)(c001 & 1023u)
             + w010 * (float)(c010 & 1023u) + w011 * (float)(c011 & 1023u)
             + w100 * (float)(c100 & 1023u) + w101 * (float)(c101 & 1023u)
             + w110 * (float)(c110 & 1023u) + w111 * (float)(c111 & 1023u);

    float a1 = w000 * (float)((c000 >> 10) & 1023u) + w001 * (float)((c001 >> 10) & 1023u)
             + w010 * (float)((c010 >> 10) & 1023u) + w011 * (float)((c011 >> 10) & 1023u)
             + w100 * (float)((c100 >> 10) & 1023u) + w101 * (float)((c101 >> 10) & 1023u)
             + w110 * (float)((c110 >> 10) & 1023u) + w111 * (float)((c111 >> 10) & 1023u);

    float a2 = w000 * (float)(c000 >> 20) + w001 * (float)(c001 >> 20)
             + w010 * (float)(c010 >> 20) + w011 * (float)(c011 >> 20)
             + w100 * (float)(c100 >> 20) + w101 * (float)(c101 >> 20)
             + w110 * (float)(c110 >> 20) + w111 * (float)(c111 >> 20);

    out0 = a0 * dq;
    out1 = a1 * dq;
    out2 = a2 * dq;
}

// process one float4 pixel-group against the LDS LUT
__device__ __forceinline__ void lut_group(const unsigned int* sLut,
                                          const float4& rv, const float4& gv, const float4& bv,
                                          float4& v0, float4& v1, float4& v2)
{
    float o00, o01, o02, o10, o11, o12, o20, o21, o22, o30, o31, o32;
    lut_px(sLut, rv.x, gv.x, bv.x, o00, o01, o02);
    lut_px(sLut, rv.y, gv.y, bv.y, o10, o11, o12);
    lut_px(sLut, rv.z, gv.z, bv.z, o20, o21, o22);
    lut_px(sLut, rv.w, gv.w, bv.w, o30, o31, o32);
    v0 = make_float4(o00, o10, o20, o30);
    v1 = make_float4(o01, o11, o21, o31);
    v2 = make_float4(o02, o12, o22, o32);
}

// ---------------------------------------------------------------------------
// Main kernel: distance-2 image prefetch. While computing image b, the loads
// for images b+1 AND b+2 are both in flight (6 outstanding float4 loads per
// wave, 2x the distance-1 scheme). This is a memory-chain-only change — the
// compiler cannot collapse it (loads are chained ops in distinct named regs) —
// targeting the sustained-MLP gap behind the 2.34 TB/s effective bandwidth.
// Compute path (lut_px) is byte-identical to all verified versions.
// ---------------------------------------------------------------------------
template <bool PREPACKED>
__global__ __launch_bounds__(1024) void lut3d_apply_kernel(
    const unsigned int* __restrict__ plut,   // packed LUT in workspace (PREPACKED)
    const float* __restrict__ lut,           // raw LUT (fallback path)
    const float* __restrict__ x,             // (8, 3, 1024, 1024)
    float* __restrict__ out)                 // (8, 3, 1024, 1024)
{
    extern __shared__ unsigned int sLut[];   // DIM3 dwords

    if constexpr (PREPACKED) {
        const uint4* p4 = reinterpret_cast<const uint4*>(plut);
        uint4* s4 = reinterpret_cast<uint4*>(sLut);
        for (int i = threadIdx.x; i < DIM3 / 4; i += 1024) s4[i] = p4[i];
        if (threadIdx.x == 0) sLut[DIM3 - 1] = plut[DIM3 - 1];
    } else {
        for (int i = threadIdx.x; i < DIM3; i += 1024) {
            float v0 = lut[i];
            float v1 = lut[DIM3 + i];
            float v2 = lut[2 * DIM3 + i];
            unsigned q0 = (unsigned)(fminf(fmaxf(v0, 0.0f), 1.0f) * 1023.0f + 0.5f);
            unsigned q1 = (unsigned)(fminf(fmaxf(v1, 0.0f), 1.0f) * 1023.0f + 0.5f);
            unsigned q2 = (unsigned)(fminf(fmaxf(v2, 0.0f), 1.0f) * 1023.0f + 0.5f);
            sLut[i] = q0 | (q1 << 10) | (q2 << 20);
        }
    }
    __syncthreads();

    const int q = blockIdx.x * blockDim.x + threadIdx.x;   // [0, GROUPS_PER_IMG)
    const float4* __restrict__ xp = reinterpret_cast<const float4*>(x);
    float4* __restrict__ op = reinterpret_cast<float4*>(out);

    auto iplane = [&](int img, int ch) -> size_t {
        return ((size_t)img * 3 + ch) * GROUPS_PER_IMG + q;
    };

    // Two rotating image-buffers; consume one while BOTH the other and the
    // re-issued one are in flight -> steady-state 6 outstanding loads/wave.
    float4 rA = xp[iplane(0, 0)], gA = xp[iplane(0, 1)], bA = xp[iplane(0, 2)];  // img 0
    float4 rB = xp[iplane(1, 0)], gB = xp[iplane(1, 1)], bB = xp[iplane(1, 2)];  // img 1

#pragma unroll 1
    for (int b = 0; b < BATCH; b += 2) {
        // ---- phase A: compute image b, refill A with image b+2 ----
        {
            float4 rv = rA, gv = gA, bv = bA;       // consume (forces vmcnt wait on A only)
            if (b + 2 < BATCH) {                    // uniform branch
                rA = xp[iplane(b + 2, 0)];
                gA = xp[iplane(b + 2, 1)];
                bA = xp[iplane(b + 2, 2)];
            }
            float4 v0, v1, v2;
            lut_group(sLut, rv, gv, bv, v0, v1, v2);
            op[iplane(b, 0)] = v0;
            op[iplane(b, 1)] = v1;
            op[iplane(b, 2)] = v2;
        }
        // ---- phase B: compute image b+1, refill B with image b+3 ----
        {
            float4 rv = rB, gv = gB, bv = bB;
            if (b + 3 < BATCH) {
                rB = xp[iplane(b + 3, 0)];
                gB = xp[iplane(b + 3, 1)];
                bB = xp[iplane(b + 3, 2)];
            }
            float4 v0, v1, v2;
            lut_group(sLut, rv, gv, bv, v0, v1, v2);
            op[iplane(b + 1, 0)] = v0;
            op[iplane(b + 1, 1)] = v1;
            op[iplane(b + 1, 2)] = v2;
        }
    }
}

extern "C" void kernel_launch(void* const* d_in, const int* in_sizes, int n_in,
                              void* d_out, int out_size, void* d_ws, size_t ws_size,
                              hipStream_t stream) {
    const float* lut = (const float*)d_in[0];  // 3*33*33*33
    const float* x   = (const float*)d_in[1];  // 8*3*1024*1024
    float* out = (float*)d_out;

    // 140 KB LDS -> 1 block/CU; 1024 threads = 16 waves/CU; 256 blocks = 1/CU.
    if (ws_size >= (size_t)LDS_BYTES && d_ws != nullptr) {
        unsigned int* packed = (unsigned int*)d_ws;
        lut_pack_kernel<<<(DIM3 + 255) / 256, 256, 0, stream>>>(lut, packed);
        lut3d_apply_kernel<true><<<256, 1024, LDS_BYTES, stream>>>(packed, lut, x, out);
    } else {
        lut3d_apply_kernel<false><<<256, 1024, LDS_BYTES, stream>>>(nullptr, lut, x, out);
    }
}